// Round 1
// baseline (156.308 us; speedup 1.0000x reference)
//
#include <hip/hip_runtime.h>

#define BB 4
#define NN 2048
#define FIN 128
#define FOUT 128
#define NH 4
#define DH 32
#define NS 0.2f
#define JP 4
#define ITILE 64
#define CHUNK 64

// ws layout (floats)
#define OFF_H   0                          // [B][H][N][D]  = 1048576
#define OFF_ES  1048576                    // [B][H][N]     = 32768
#define OFF_ED  1081344                    // [B][H][N]     = 32768
#define OFF_PA  1114112                    // [JP][B][H][N][D] = 4194304
#define OFF_PS  5308416                    // [JP][B][H][N] = 131072

// ---------------- K1: projection + e_src/e_dst -------------------
__global__ __launch_bounds__(128) void k_proj(
    const float* __restrict__ x, const float* __restrict__ W,
    const float* __restrict__ a, float* __restrict__ h_t,
    float* __restrict__ e_src, float* __restrict__ e_dst) {
  __shared__ float Ws[FIN * FOUT];  // [k][f], same layout as global
  const int f = threadIdx.x;        // 0..127
  // stage W (16384 floats, 128 threads x 32 float4)
  const float4* Wg4 = (const float4*)W;
  float4* Ws4 = (float4*)Ws;
#pragma unroll
  for (int t = 0; t < 32; ++t) Ws4[t * 128 + f] = Wg4[t * 128 + f];
  __syncthreads();

  const int rb = blockIdx.x * 16;   // global row in [0, B*N)
  const int head = f >> 5, d = f & 31;
  const float a_s = a[head * (2 * DH) + d];
  const float a_d = a[head * (2 * DH) + DH + d];

  float acc[16];
#pragma unroll
  for (int r = 0; r < 16; ++r) acc[r] = 0.f;

  const float* xb = x + (size_t)rb * FIN;  // block-uniform base -> s_loads
  for (int k = 0; k < FIN; ++k) {
    float wv = Ws[k * FOUT + f];           // conflict-free (bank = f%32)
#pragma unroll
    for (int r = 0; r < 16; ++r) acc[r] = fmaf(wv, xb[r * FIN + k], acc[r]);
  }

#pragma unroll
  for (int r = 0; r < 16; ++r) {
    const int g = rb + r;
    const int b = g >> 11, n = g & (NN - 1);
    // store h head-major
    h_t[(((size_t)b * NH + head) * NN + n) * DH + d] = acc[r];
    // e_src / e_dst: reduce over d within 32-lane group
    float s1 = acc[r] * a_s;
    float s2 = acc[r] * a_d;
#pragma unroll
    for (int off = 16; off >= 1; off >>= 1) {
      s1 += __shfl_xor(s1, off);
      s2 += __shfl_xor(s2, off);
    }
    if (d == 0) {
      e_src[((size_t)b * NH + head) * NN + n] = s1;
      e_dst[((size_t)b * NH + head) * NN + n] = s2;
    }
  }
}

// ---------------- K2: masked softmax-weighted aggregation ---------
__global__ __launch_bounds__(256) void k_attn(
    const float* __restrict__ h_t, const float* __restrict__ e_src,
    const float* __restrict__ e_dst, const int* __restrict__ adj,
    float* __restrict__ pacc, float* __restrict__ pS) {
  __shared__ float hbuf[NH][CHUNK][DH];  // 32 KB

  const int bid = blockIdx.x;            // JP * B * (N/ITILE) = 512
  const int tiles = NN / ITILE;          // 32
  const int jp = bid / (BB * tiles);
  const int rem = bid % (BB * tiles);
  const int b = rem / tiles;
  const int it = rem % tiles;

  const int w = threadIdx.x >> 6;
  const int lane = threadIdx.x & 63;
  const int bh = __builtin_amdgcn_readfirstlane(b * NH + w);

  const float* ed = e_dst + (size_t)bh * NN;

  // unmasked max of e_dst over full row (same value for every partition)
  float m = -1e30f;
#pragma unroll
  for (int t = 0; t < NN / 64; ++t) m = fmaxf(m, ed[t * 64 + lane]);
#pragma unroll
  for (int off = 32; off >= 1; off >>= 1) m = fmaxf(m, __shfl_xor(m, off));

  const int i = it * ITILE + lane;
  const float esi = e_src[(size_t)bh * NN + i];
  const float mi_raw = esi + m;
  const float mi = mi_raw > 0.f ? mi_raw : NS * mi_raw;  // lrelu (monotone) upper bound

  float acc[DH];
#pragma unroll
  for (int q = 0; q < DH; ++q) acc[q] = 0.f;
  float S = 0.f;

  const int* adjrow = adj + ((size_t)b * NN + i) * NN;
  const float* hsrc = h_t + (size_t)bh * NN * DH;
  const int j_base = jp * (NN / JP);

  for (int c = 0; c < (NN / JP) / CHUNK; ++c) {
    const int j0 = j_base + c * CHUNK;
    __syncthreads();
    // wave w stages its head's [64][32] chunk (contiguous slab)
    const float4* src4 = (const float4*)(hsrc + (size_t)j0 * DH);
    float4* dst4 = (float4*)&hbuf[w][0][0];
#pragma unroll
    for (int t = 0; t < 8; ++t) dst4[t * 64 + lane] = src4[t * 64 + lane];
    __syncthreads();

#pragma unroll
    for (int jq = 0; jq < CHUNK / 4; ++jq) {
      const int4 av = *reinterpret_cast<const int4*>(adjrow + j0 + jq * 4);
#pragma unroll
      for (int u = 0; u < 4; ++u) {
        const int jj = jq * 4 + u;
        const float edj = ed[j0 + jj];         // uniform -> s_load
        const float er = esi + edj;
        const float e = er > 0.f ? er : NS * er;
        float wgt = __expf(e - mi);
        const int ad = ((const int*)&av)[u];
        wgt = ad ? wgt : 0.f;
        S += wgt;
        const float4* hv4 = (const float4*)&hbuf[w][jj][0];
#pragma unroll
        for (int q = 0; q < 8; ++q) {
          const float4 hv = hv4[q];            // uniform addr -> broadcast
          acc[q * 4 + 0] = fmaf(wgt, hv.x, acc[q * 4 + 0]);
          acc[q * 4 + 1] = fmaf(wgt, hv.y, acc[q * 4 + 1]);
          acc[q * 4 + 2] = fmaf(wgt, hv.z, acc[q * 4 + 2]);
          acc[q * 4 + 3] = fmaf(wgt, hv.w, acc[q * 4 + 3]);
        }
      }
    }
  }

  float* pa = pacc + ((((size_t)jp * BB + b) * NH + w) * NN + i) * DH;
  float4* pa4 = (float4*)pa;
#pragma unroll
  for (int q = 0; q < 8; ++q)
    pa4[q] = make_float4(acc[q * 4 + 0], acc[q * 4 + 1], acc[q * 4 + 2], acc[q * 4 + 3]);
  pS[(((size_t)jp * BB + b) * NH + w) * NN + i] = S;
}

// ---------------- K3: combine partials + elu ----------------------
__global__ __launch_bounds__(256) void k_comb(
    const float* __restrict__ pacc, const float* __restrict__ pS,
    float* __restrict__ out) {
  const int idx = blockIdx.x * 256 + threadIdx.x;  // < B*N*128
  const int f = idx & 127;
  const int g = idx >> 7;             // b*N + n
  const int b = g >> 11, n = g & (NN - 1);
  const int head = f >> 5, d = f & 31;
  const size_t base = (((size_t)b * NH + head) * NN + n) * DH + d;
  const size_t sbase = ((size_t)b * NH + head) * NN + n;
  float v = 0.f, s = 0.f;
#pragma unroll
  for (int p = 0; p < JP; ++p) {
    v += pacc[(size_t)p * (BB * NH * NN * DH) + base];
    s += pS[(size_t)p * (BB * NH * NN) + sbase];
  }
  const float o = v / s;
  out[idx] = o > 0.f ? o : (__expf(o) - 1.f);
}

extern "C" void kernel_launch(void* const* d_in, const int* in_sizes, int n_in,
                              void* d_out, int out_size, void* d_ws, size_t ws_size,
                              hipStream_t stream) {
  const float* x = (const float*)d_in[0];
  const int* adj = (const int*)d_in[1];
  const float* W = (const float*)d_in[2];
  const float* a = (const float*)d_in[3];
  float* out = (float*)d_out;
  float* ws = (float*)d_ws;

  float* h_t = ws + OFF_H;
  float* e_src = ws + OFF_ES;
  float* e_dst = ws + OFF_ED;
  float* pacc = ws + OFF_PA;
  float* pS = ws + OFF_PS;

  k_proj<<<(BB * NN) / 16, 128, 0, stream>>>(x, W, a, h_t, e_src, e_dst);
  k_attn<<<JP * BB * (NN / ITILE), 256, 0, stream>>>(h_t, e_src, e_dst, adj, pacc, pS);
  k_comb<<<(BB * NN * FOUT) / 256, 256, 0, stream>>>(pacc, pS, out);
}

// Round 2
// 99.718 us; speedup vs baseline: 1.5675x; 1.5675x over previous
//
#include <hip/hip_runtime.h>

#define BB 4
#define NN 2048
#define FIN 128
#define FOUT 128
#define NH 4
#define DH 32
#define NS 0.2f
#define JP 2
#define ITILE 64   // rows per k_attn block (4 waves x 16)

typedef unsigned short u16;
typedef __attribute__((ext_vector_type(8))) short short8;
typedef __attribute__((ext_vector_type(4))) float f32x4;

// ws layout (float offsets)
#define OFF_ES 0                      // [BH][N]            32768
#define OFF_ED 32768                  // [BH][N]            32768
#define OFF_PS 65536                  // [JP][BH][N]        65536
#define OFF_PA 131072                 // [JP][BH][N][32]    2097152
#define OFF_HT 2228224                // bf16 [BH][32][N]   524288 u16 = 262144 f
#define PA_STRIDE ((size_t)16 * NN * 32)   // floats per jp slice
#define PS_STRIDE ((size_t)16 * NN)

__device__ __forceinline__ u16 f2bf_rne(float f) {
  unsigned u = __float_as_uint(f);
  return (u16)((u + 0x7fffu + ((u >> 16) & 1u)) >> 16);
}

// ---------------- K1: projection + e_src/e_dst + bf16 transposed h ----------
__global__ __launch_bounds__(128) void k_proj(
    const float* __restrict__ x, const float* __restrict__ W,
    const float* __restrict__ a, u16* __restrict__ hT,
    float* __restrict__ e_src, float* __restrict__ e_dst) {
  __shared__ float Ws[FIN * FOUT];
  const int f = threadIdx.x;  // 0..127 : head*32 + d
  const float4* Wg4 = (const float4*)W;
  float4* Ws4 = (float4*)Ws;
#pragma unroll
  for (int t = 0; t < 32; ++t) Ws4[t * 128 + f] = Wg4[t * 128 + f];
  __syncthreads();

  const int rb = blockIdx.x * 16;  // 16 rows, all within one b
  const int head = f >> 5, d = f & 31;
  const int b = rb >> 11, n0 = rb & (NN - 1);
  const int bh = b * NH + head;
  const float a_s = a[head * (2 * DH) + d];
  const float a_d = a[head * (2 * DH) + DH + d];

  float acc[16];
#pragma unroll
  for (int r = 0; r < 16; ++r) acc[r] = 0.f;

  const float* xb = x + (size_t)rb * FIN;
  for (int k = 0; k < FIN; ++k) {
    float wv = Ws[k * FOUT + f];
#pragma unroll
    for (int r = 0; r < 16; ++r) acc[r] = fmaf(wv, xb[r * FIN + k], acc[r]);
  }

  // bf16 transposed store: hT[bh][d][n0..n0+16]
  u16 hs[16];
#pragma unroll
  for (int r = 0; r < 16; ++r) hs[r] = f2bf_rne(acc[r]);
  u16* dst = hT + ((size_t)bh * DH + d) * NN + n0;
  *(int4*)dst = *(int4*)&hs[0];
  *(int4*)(dst + 8) = *(int4*)&hs[8];

#pragma unroll
  for (int r = 0; r < 16; ++r) {
    float s1 = acc[r] * a_s;
    float s2 = acc[r] * a_d;
#pragma unroll
    for (int off = 16; off >= 1; off >>= 1) {
      s1 += __shfl_xor(s1, off);
      s2 += __shfl_xor(s2, off);
    }
    if (d == 0) {
      e_src[(size_t)bh * NN + n0 + r] = s1;
      e_dst[(size_t)bh * NN + n0 + r] = s2;
    }
  }
}

// ---------------- K2: masked softmax weights -> MFMA aggregation ------------
__global__ __launch_bounds__(256) void k_attn(
    const u16* __restrict__ hT, const float* __restrict__ e_src,
    const float* __restrict__ e_dst, const int* __restrict__ adj,
    float* __restrict__ pacc, float* __restrict__ pS) {
  const int tiles = NN / ITILE;  // 32
  const int bid = blockIdx.x;    // JP * 16 * tiles = 1024
  const int jp = bid / (16 * tiles);
  const int rem = bid % (16 * tiles);
  const int bh = rem / tiles;
  const int it = rem % tiles;
  const int b = bh >> 2;

  const int w = threadIdx.x >> 6;
  const int lane = threadIdx.x & 63;
  const int lg = lane >> 4;  // k-group
  const int lm = lane & 15;  // A-row / B-col

  const float* ed = e_dst + (size_t)bh * NN;
  // unmasked max of e_dst over the FULL row (jp-consistent shift)
  float m = -1e30f;
#pragma unroll
  for (int t = 0; t < NN / 64; ++t) m = fmaxf(m, ed[t * 64 + lane]);
#pragma unroll
  for (int off = 32; off >= 1; off >>= 1) m = fmaxf(m, __shfl_xor(m, off));

  const int i = it * ITILE + w * 16 + lm;  // this lane's weight row
  const float esi = e_src[(size_t)bh * NN + i];
  const float mr = esi + m;
  const float mi = fmaxf(mr, NS * mr);  // lrelu (monotone) upper bound

  f32x4 acc0 = {0.f, 0.f, 0.f, 0.f};
  f32x4 acc1 = {0.f, 0.f, 0.f, 0.f};
  float S = 0.f;

  const int* arow = adj + ((size_t)b * NN + i) * NN;
  const u16* hb0 = hT + ((size_t)bh * DH + lm) * NN;
  const u16* hb1 = hT + ((size_t)bh * DH + 16 + lm) * NN;

  const int jbeg = jp * (NN / JP);
  for (int c = 0; c < (NN / JP) / 32; ++c) {
    const int jj = jbeg + c * 32 + lg * 8;
    const float4 ev0 = *(const float4*)(ed + jj);
    const float4 ev1 = *(const float4*)(ed + jj + 4);
    const int4 a0 = *(const int4*)(arow + jj);
    const int4 a1 = *(const int4*)(arow + jj + 4);
    const short8 bf0 = *(const short8*)(hb0 + jj);
    const short8 bf1 = *(const short8*)(hb1 + jj);
    const float evs[8] = {ev0.x, ev0.y, ev0.z, ev0.w, ev1.x, ev1.y, ev1.z, ev1.w};
    const int as_[8] = {a0.x, a0.y, a0.z, a0.w, a1.x, a1.y, a1.z, a1.w};
    short8 af;
#pragma unroll
    for (int e = 0; e < 8; ++e) {
      const float er = esi + evs[e];
      const float arg = fmaxf(er, NS * er) - mi;
      float wv = __expf(arg);
      wv = as_[e] ? wv : 0.f;
      S += wv;
      af[e] = (short)f2bf_rne(wv);
    }
    acc0 = __builtin_amdgcn_mfma_f32_16x16x32_bf16(af, bf0, acc0, 0, 0, 0);
    acc1 = __builtin_amdgcn_mfma_f32_16x16x32_bf16(af, bf1, acc1, 0, 0, 0);
  }

  // total denominator for row lm over this jp range
  S += __shfl_xor(S, 16);
  S += __shfl_xor(S, 32);

  float* pa = pacc + ((size_t)jp * 16 + bh) * NN * 32;
#pragma unroll
  for (int r = 0; r < 4; ++r) {
    const int row = it * ITILE + w * 16 + lg * 4 + r;
    pa[(size_t)row * 32 + lm] = acc0[r];
    pa[(size_t)row * 32 + 16 + lm] = acc1[r];
  }
  if (lane < 16) pS[((size_t)jp * 16 + bh) * NN + i] = S;
}

// ---------------- K3: combine partials + elu --------------------------------
__global__ __launch_bounds__(256) void k_comb(
    const float* __restrict__ pacc, const float* __restrict__ pS,
    float* __restrict__ out) {
  const int idx = blockIdx.x * 256 + threadIdx.x;  // < B*N*128
  const int f = idx & 127;
  const int g = idx >> 7;
  const int b = g >> 11, n = g & (NN - 1);
  const int head = f >> 5, d = f & 31;
  const int bh = b * NH + head;
  const size_t base = ((size_t)bh * NN + n) * 32 + d;
  const size_t sbase = (size_t)bh * NN + n;
  float v = pacc[base] + pacc[PA_STRIDE + base];
  float s = pS[sbase] + pS[PS_STRIDE + sbase];
  const float o = v / s;
  out[idx] = o > 0.f ? o : (__expf(o) - 1.f);
}

extern "C" void kernel_launch(void* const* d_in, const int* in_sizes, int n_in,
                              void* d_out, int out_size, void* d_ws, size_t ws_size,
                              hipStream_t stream) {
  const float* x = (const float*)d_in[0];
  const int* adj = (const int*)d_in[1];
  const float* W = (const float*)d_in[2];
  const float* a = (const float*)d_in[3];
  float* out = (float*)d_out;
  float* ws = (float*)d_ws;

  float* e_src = ws + OFF_ES;
  float* e_dst = ws + OFF_ED;
  float* pS = ws + OFF_PS;
  float* pacc = ws + OFF_PA;
  u16* hT = (u16*)(ws + OFF_HT);

  k_proj<<<(BB * NN) / 16, 128, 0, stream>>>(x, W, a, hT, e_src, e_dst);
  k_attn<<<JP * BB * NH * (NN / ITILE), 256, 0, stream>>>(hT, e_src, e_dst, adj, pacc, pS);
  k_comb<<<(BB * NN * FOUT) / 256, 256, 0, stream>>>(pacc, pS, out);
}

// Round 3
// 94.330 us; speedup vs baseline: 1.6570x; 1.0571x over previous
//
#include <hip/hip_runtime.h>
#include <hip/hip_bf16.h>

#define BB 4
#define NN 2048
#define FIN 128
#define NH 4
#define DH 32
#define NS 0.2f

typedef unsigned short u16;
typedef __attribute__((ext_vector_type(8))) short short8;
typedef __attribute__((ext_vector_type(4))) float f32x4;

// ws float offsets
#define OFF_ES 0          // [16][2048]
#define OFF_ED 32768      // [16][2048]
#define OFF_P  65536      // [16][2048]
#define OFF_Q  98304      // [16][2048]
#define OFF_M  131072     // [16]
#define OFF_HT 131088     // u16 [16][32][2048] = 262144 floats

__device__ __forceinline__ u16 f2bf_rne(float f) {
  unsigned u = __float_as_uint(f);
  return (u16)((u + 0x7fffu + ((u >> 16) & 1u)) >> 16);
}

// ---------------- K1: projection + e_src/e_dst + bf16 transposed h ----------
__global__ __launch_bounds__(256) void k_proj(
    const float* __restrict__ x, const float* __restrict__ W,
    const float* __restrict__ a, u16* __restrict__ hT,
    float* __restrict__ e_src, float* __restrict__ e_dst) {
  __shared__ float Ws[FIN * 128];
  const int tid = threadIdx.x;
  const int f = tid & 127, g = tid >> 7;
  const float4* Wg4 = (const float4*)W;
  float4* Ws4 = (float4*)Ws;
#pragma unroll
  for (int t = 0; t < 16; ++t) Ws4[t * 256 + tid] = Wg4[t * 256 + tid];
  __syncthreads();

  const int rb = blockIdx.x * 32 + g * 16;  // 16 rows for this half
  const int head = f >> 5, d = f & 31;
  const int b = rb >> 11, n0 = rb & (NN - 1);
  const int bh = b * NH + head;
  const float a_s = a[head * (2 * DH) + d];
  const float a_d = a[head * (2 * DH) + DH + d];

  float acc[16];
#pragma unroll
  for (int r = 0; r < 16; ++r) acc[r] = 0.f;

  const float* xb = x + (size_t)rb * FIN;  // wave-uniform -> s_loads
  for (int k = 0; k < FIN; ++k) {
    const float wv = Ws[k * 128 + f];
#pragma unroll
    for (int r = 0; r < 16; ++r) acc[r] = fmaf(wv, xb[r * FIN + k], acc[r]);
  }

  // bf16 transposed store hT[bh][d][n0..n0+16]
  u16 hs[16];
#pragma unroll
  for (int r = 0; r < 16; ++r) hs[r] = f2bf_rne(acc[r]);
  u16* dst = hT + ((size_t)bh * DH + d) * NN + n0;
  *(int4*)dst = *(int4*)&hs[0];
  *(int4*)(dst + 8) = *(int4*)&hs[8];

#pragma unroll
  for (int r = 0; r < 16; ++r) {
    float s1 = acc[r] * a_s;
    float s2 = acc[r] * a_d;
#pragma unroll
    for (int off = 16; off >= 1; off >>= 1) {
      s1 += __shfl_xor(s1, off);
      s2 += __shfl_xor(s2, off);
    }
    if (d == 0) {
      e_src[(size_t)bh * NN + n0 + r] = s1;
      e_dst[(size_t)bh * NN + n0 + r] = s2;
    }
  }
}

// ---------------- K1.5: per-bh max + P/Q tables ------------------------------
__global__ __launch_bounds__(64) void k_prep(
    const float* __restrict__ e_dst, float* __restrict__ P,
    float* __restrict__ Q, float* __restrict__ M) {
  const int bh = blockIdx.x >> 2, qd = blockIdx.x & 3;
  const int lane = threadIdx.x;
  const float* ed = e_dst + (size_t)bh * NN;
  float m = -1e30f;
#pragma unroll
  for (int t = 0; t < 32; ++t) m = fmaxf(m, ed[t * 64 + lane]);
#pragma unroll
  for (int off = 32; off >= 1; off >>= 1) m = fmaxf(m, __shfl_xor(m, off));
  if (qd == 0 && lane == 0) M[bh] = m;
#pragma unroll
  for (int t = 0; t < 8; ++t) {
    const int j = qd * 512 + t * 64 + lane;
    const float e = ed[j];
    P[(size_t)bh * NN + j] = __expf(e);
    Q[(size_t)bh * NN + j] = __expf(NS * e);
  }
}

// ---------------- K2: masked softmax weights -> MFMA -> direct output -------
__global__ __launch_bounds__(256) void k_attn(
    const u16* __restrict__ hT, const float* __restrict__ e_src,
    const float* __restrict__ Pv, const float* __restrict__ Qv,
    const float* __restrict__ Mv, const int* __restrict__ adj,
    float* __restrict__ out) {
  __shared__ float part[4][32][33];
  __shared__ float sp[4][2][16];

  const int bid = blockIdx.x;          // 16 bh x 64 row-tiles
  const int bh = bid >> 6;
  const int it = bid & 63;
  const int b = bh >> 2, head = bh & 3;

  const int w = threadIdx.x >> 6;      // j-quarter
  const int lane = threadIdx.x & 63;
  const int lg = lane >> 4, lm = lane & 15;

  const int i0 = it * 32 + lm;         // this lane's two weight rows
  const int i1 = i0 + 16;
  const float m = Mv[bh];
  const float es0 = e_src[(size_t)bh * NN + i0];
  const float es1 = e_src[(size_t)bh * NN + i1];
  const float mr0 = es0 + m, mr1 = es1 + m;
  const float mi0 = fmaxf(mr0, NS * mr0), mi1 = fmaxf(mr1, NS * mr1);
  const float A0 = __expf(es0 - mi0), B0 = __expf(NS * es0 - mi0);
  const float A1 = __expf(es1 - mi1), B1 = __expf(NS * es1 - mi1);
  const float T0 = __expf(-es0), T1 = __expf(-es1);  // P>T  <=>  esi+edj>0

  const float* Pb = Pv + (size_t)bh * NN;
  const float* Qb = Qv + (size_t)bh * NN;
  const int* ar0 = adj + ((size_t)b * NN + i0) * NN;
  const int* ar1 = adj + ((size_t)b * NN + i1) * NN;
  const u16* hb0 = hT + ((size_t)bh * DH + lm) * NN;
  const u16* hb1 = hT + ((size_t)bh * DH + 16 + lm) * NN;

  f32x4 acc00 = {0,0,0,0}, acc01 = {0,0,0,0};
  f32x4 acc10 = {0,0,0,0}, acc11 = {0,0,0,0};
  float S0 = 0.f, S1 = 0.f;

  const int jbase = w * 512 + lg * 8;
#pragma unroll 2
  for (int jq = 0; jq < 16; ++jq) {
    const int jj = jbase + jq * 32;
    const float4 p0 = *(const float4*)(Pb + jj);
    const float4 p1 = *(const float4*)(Pb + jj + 4);
    const float4 q0 = *(const float4*)(Qb + jj);
    const float4 q1 = *(const float4*)(Qb + jj + 4);
    const int4 a00 = *(const int4*)(ar0 + jj);
    const int4 a01 = *(const int4*)(ar0 + jj + 4);
    const int4 a10 = *(const int4*)(ar1 + jj);
    const int4 a11 = *(const int4*)(ar1 + jj + 4);
    const short8 hv0 = *(const short8*)(hb0 + jj);
    const short8 hv1 = *(const short8*)(hb1 + jj);
    const float pp[8] = {p0.x, p0.y, p0.z, p0.w, p1.x, p1.y, p1.z, p1.w};
    const float qq[8] = {q0.x, q0.y, q0.z, q0.w, q1.x, q1.y, q1.z, q1.w};
    const int aa0[8] = {a00.x, a00.y, a00.z, a00.w, a01.x, a01.y, a01.z, a01.w};
    const int aa1[8] = {a10.x, a10.y, a10.z, a10.w, a11.x, a11.y, a11.z, a11.w};
    short8 af0, af1;
#pragma unroll
    for (int e = 0; e < 8; ++e) {
      const bool c0 = pp[e] > T0;
      float w0 = (c0 ? A0 : B0) * (c0 ? pp[e] : qq[e]);
      w0 = aa0[e] ? w0 : 0.f;
      S0 += w0;
      af0[e] = (short)__builtin_bit_cast(unsigned short, __float2bfloat16(w0));
      const bool c1 = pp[e] > T1;
      float w1 = (c1 ? A1 : B1) * (c1 ? pp[e] : qq[e]);
      w1 = aa1[e] ? w1 : 0.f;
      S1 += w1;
      af1[e] = (short)__builtin_bit_cast(unsigned short, __float2bfloat16(w1));
    }
    acc00 = __builtin_amdgcn_mfma_f32_16x16x32_bf16(af0, hv0, acc00, 0, 0, 0);
    acc01 = __builtin_amdgcn_mfma_f32_16x16x32_bf16(af0, hv1, acc01, 0, 0, 0);
    acc10 = __builtin_amdgcn_mfma_f32_16x16x32_bf16(af1, hv0, acc10, 0, 0, 0);
    acc11 = __builtin_amdgcn_mfma_f32_16x16x32_bf16(af1, hv1, acc11, 0, 0, 0);
  }

  // denominator over this wave's j-quarter (sum the 4 k-groups)
  S0 += __shfl_xor(S0, 16); S0 += __shfl_xor(S0, 32);
  S1 += __shfl_xor(S1, 16); S1 += __shfl_xor(S1, 32);

#pragma unroll
  for (int r = 0; r < 4; ++r) {
    const int rl = lg * 4 + r;   // C row = (lane>>4)*4 + reg
    part[w][rl][lm] = acc00[r];
    part[w][rl][16 + lm] = acc01[r];
    part[w][16 + rl][lm] = acc10[r];
    part[w][16 + rl][16 + lm] = acc11[r];
  }
  if (lg == 0) { sp[w][0][lm] = S0; sp[w][1][lm] = S1; }
  __syncthreads();

  const int tid = threadIdx.x;
#pragma unroll
  for (int t = 0; t < 4; ++t) {
    const int idx = t * 256 + tid;
    const int row = idx >> 5, d = idx & 31;
    const float v = part[0][row][d] + part[1][row][d] +
                    part[2][row][d] + part[3][row][d];
    const float s = sp[0][row >> 4][row & 15] + sp[1][row >> 4][row & 15] +
                    sp[2][row >> 4][row & 15] + sp[3][row >> 4][row & 15];
    const float o = v / s;
    const int n = it * 32 + row;
    out[((size_t)b * NN + n) * 128 + head * 32 + d] =
        o > 0.f ? o : (__expf(o) - 1.f);
  }
}

extern "C" void kernel_launch(void* const* d_in, const int* in_sizes, int n_in,
                              void* d_out, int out_size, void* d_ws, size_t ws_size,
                              hipStream_t stream) {
  const float* x = (const float*)d_in[0];
  const int* adj = (const int*)d_in[1];
  const float* W = (const float*)d_in[2];
  const float* a = (const float*)d_in[3];
  float* out = (float*)d_out;
  float* ws = (float*)d_ws;

  float* e_src = ws + OFF_ES;
  float* e_dst = ws + OFF_ED;
  float* Pv = ws + OFF_P;
  float* Qv = ws + OFF_Q;
  float* Mv = ws + OFF_M;
  u16* hT = (u16*)(ws + OFF_HT);

  k_proj<<<(BB * NN) / 32, 256, 0, stream>>>(x, W, a, hT, e_src, e_dst);
  k_prep<<<BB * NH * 4, 64, 0, stream>>>(e_dst, Pv, Qv, Mv);
  k_attn<<<BB * NH * 64, 256, 0, stream>>>(hT, e_src, Pv, Qv, Mv, adj, out);
}

// Round 5
// 69.054 us; speedup vs baseline: 2.2636x; 1.3660x over previous
//
#include <hip/hip_runtime.h>
#include <hip/hip_bf16.h>

#define BB 4
#define NN 2048
#define FIN 128
#define NH 4
#define DH 32
#define NS 0.2f

typedef unsigned int u32;
typedef unsigned short u16;
typedef unsigned long long u64;
typedef __attribute__((ext_vector_type(8))) short short8;
typedef __attribute__((ext_vector_type(4))) float f32x4;

// ws float offsets
#define OFF_ES 0          // [16][2048]
#define OFF_ED 32768      // [16][2048]
#define OFF_P  65536      // [16][2048]
#define OFF_Q  98304      // [16][2048]
#define OFF_M  131072     // [16]
#define OFF_HT 131088     // u16 [16][32][2048] = 1048576 u16 = 524288 floats
#define OFF_BITS 655376   // u32 [4][2048][64] = 524288 u32 (= OFF_HT + 524288)

__device__ __forceinline__ u16 f2bf_rne(float f) {
  unsigned u = __float_as_uint(f);
  return (u16)((u + 0x7fffu + ((u >> 16) & 1u)) >> 16);
}

// ---------------- K0: pack adj -> bitmask -----------------------------------
__global__ __launch_bounds__(256) void k_pack(const int* __restrict__ adj,
                                              u32* __restrict__ bits) {
  const int row = (blockIdx.x << 2) | (threadIdx.x >> 6);  // 0..8191 = b*2048+i
  const int lane = threadIdx.x & 63;
  const int* src = adj + (size_t)row * NN;
  u32* dst = bits + (size_t)row * 64;
#pragma unroll 8
  for (int it = 0; it < 32; ++it) {
    const int v = src[it * 64 + lane];
    const u64 m = __ballot(v != 0);
    if (lane == 0) *(u64*)(dst + it * 2) = m;
  }
}

// ---------------- K1: projection + e_src/e_dst + bf16 transposed h ----------
__global__ __launch_bounds__(256) void k_proj(
    const float* __restrict__ x, const float* __restrict__ W,
    const float* __restrict__ a, u16* __restrict__ hT,
    float* __restrict__ e_src, float* __restrict__ e_dst) {
  __shared__ float Ws[FIN * 128];
  const int tid = threadIdx.x;
  const int f = tid & 127, g = tid >> 7;
  const float4* Wg4 = (const float4*)W;
  float4* Ws4 = (float4*)Ws;
#pragma unroll
  for (int t = 0; t < 16; ++t) Ws4[t * 256 + tid] = Wg4[t * 256 + tid];
  __syncthreads();

  const int rb = blockIdx.x * 16 + g * 8;  // 8 rows for this half
  const int head = f >> 5, d = f & 31;
  const int b = rb >> 11, n0 = rb & (NN - 1);
  const int bh = b * NH + head;
  const float a_s = a[head * (2 * DH) + d];
  const float a_d = a[head * (2 * DH) + DH + d];

  float acc[8];
#pragma unroll
  for (int r = 0; r < 8; ++r) acc[r] = 0.f;

  const float* xb = x + (size_t)rb * FIN;  // wave-uniform -> s_loads
  for (int k = 0; k < FIN; ++k) {
    const float wv = Ws[k * 128 + f];
#pragma unroll
    for (int r = 0; r < 8; ++r) acc[r] = fmaf(wv, xb[r * FIN + k], acc[r]);
  }

  // bf16 transposed store hT[bh][d][n0..n0+8]
  u16 hs[8];
#pragma unroll
  for (int r = 0; r < 8; ++r) hs[r] = f2bf_rne(acc[r]);
  u16* dst = hT + ((size_t)bh * DH + d) * NN + n0;
  *(int4*)dst = *(int4*)&hs[0];

#pragma unroll
  for (int r = 0; r < 8; ++r) {
    float s1 = acc[r] * a_s;
    float s2 = acc[r] * a_d;
#pragma unroll
    for (int off = 16; off >= 1; off >>= 1) {
      s1 += __shfl_xor(s1, off);
      s2 += __shfl_xor(s2, off);
    }
    if (d == 0) {
      e_src[(size_t)bh * NN + n0 + r] = s1;
      e_dst[(size_t)bh * NN + n0 + r] = s2;
    }
  }
}

// ---------------- K1.5: per-bh max + P/Q tables ------------------------------
__global__ __launch_bounds__(64) void k_prep(
    const float* __restrict__ e_dst, float* __restrict__ P,
    float* __restrict__ Q, float* __restrict__ M) {
  const int bh = blockIdx.x >> 3, seg = blockIdx.x & 7;
  const int lane = threadIdx.x;
  const float* ed = e_dst + (size_t)bh * NN;
  float m = -1e30f;
#pragma unroll
  for (int t = 0; t < 32; ++t) m = fmaxf(m, ed[t * 64 + lane]);
#pragma unroll
  for (int off = 32; off >= 1; off >>= 1) m = fmaxf(m, __shfl_xor(m, off));
  if (seg == 0 && lane == 0) M[bh] = m;
#pragma unroll
  for (int t = 0; t < 4; ++t) {
    const int j = seg * 256 + t * 64 + lane;
    const float e = ed[j];
    P[(size_t)bh * NN + j] = __expf(e);
    Q[(size_t)bh * NN + j] = __expf(NS * e);
  }
}

// ---------------- K2: masked softmax weights -> MFMA -> direct output -------
__global__ __launch_bounds__(256) void k_attn(
    const u16* __restrict__ hT, const float* __restrict__ e_src,
    const float* __restrict__ Pv, const float* __restrict__ Qv,
    const float* __restrict__ Mv, const u32* __restrict__ bits,
    float* __restrict__ out) {
  __shared__ float part[4][32][33];
  __shared__ float sp[4][2][16];

  const int bid = blockIdx.x;          // 16 bh x 64 row-tiles
  const int bh = bid >> 6;
  const int it = bid & 63;
  const int b = bh >> 2, head = bh & 3;

  const int w = threadIdx.x >> 6;      // j-quarter
  const int lane = threadIdx.x & 63;
  const int lg = lane >> 4, lm = lane & 15;

  const int i0 = it * 32 + lm;         // this lane's two weight rows
  const int i1 = i0 + 16;
  const float m = Mv[bh];
  const float es0 = e_src[(size_t)bh * NN + i0];
  const float es1 = e_src[(size_t)bh * NN + i1];
  const float mr0 = es0 + m, mr1 = es1 + m;
  const float mi0 = fmaxf(mr0, NS * mr0), mi1 = fmaxf(mr1, NS * mr1);
  const float A0 = __expf(es0 - mi0), B0 = __expf(NS * es0 - mi0);
  const float A1 = __expf(es1 - mi1), B1 = __expf(NS * es1 - mi1);
  const float T0 = __expf(-es0), T1 = __expf(-es1);  // P>T  <=>  esi+edj>0

  const float* Pb = Pv + (size_t)bh * NN;
  const float* Qb = Qv + (size_t)bh * NN;
  const u16* hb0 = hT + ((size_t)bh * DH + lm) * NN;
  const u16* hb1 = hT + ((size_t)bh * DH + 16 + lm) * NN;
  const u32* br0 = bits + ((size_t)b * NN + i0) * 64 + w * 16;
  const u32* br1 = bits + ((size_t)b * NN + i1) * 64 + w * 16;
  const int shamt = lg * 8;

  f32x4 acc00 = {0,0,0,0}, acc01 = {0,0,0,0};
  f32x4 acc10 = {0,0,0,0}, acc11 = {0,0,0,0};
  float S0 = 0.f, S1 = 0.f;

  const int jbase = w * 512 + lg * 8;
  for (int jo = 0; jo < 4; ++jo) {
    const int4 bq0 = *(const int4*)(br0 + jo * 4);
    const int4 bq1 = *(const int4*)(br1 + jo * 4);
    const int wa0[4] = {bq0.x, bq0.y, bq0.z, bq0.w};
    const int wa1[4] = {bq1.x, bq1.y, bq1.z, bq1.w};
#pragma unroll
    for (int ju = 0; ju < 4; ++ju) {
      const int jj = jbase + jo * 128 + ju * 32;
      const float4 p0 = *(const float4*)(Pb + jj);
      const float4 p1 = *(const float4*)(Pb + jj + 4);
      const float4 q0 = *(const float4*)(Qb + jj);
      const float4 q1 = *(const float4*)(Qb + jj + 4);
      const short8 hv0 = *(const short8*)(hb0 + jj);
      const short8 hv1 = *(const short8*)(hb1 + jj);
      const u32 wsh0 = ((u32)wa0[ju]) >> shamt;
      const u32 wsh1 = ((u32)wa1[ju]) >> shamt;
      const float pp[8] = {p0.x, p0.y, p0.z, p0.w, p1.x, p1.y, p1.z, p1.w};
      const float qq[8] = {q0.x, q0.y, q0.z, q0.w, q1.x, q1.y, q1.z, q1.w};
      short8 af0, af1;
#pragma unroll
      for (int e = 0; e < 8; ++e) {
        const int m0 = (int)(wsh0 << (31 - e)) >> 31;  // bit e replicated
        const int m1 = (int)(wsh1 << (31 - e)) >> 31;
        const bool c0 = pp[e] > T0;
        float w0 = (c0 ? A0 : B0) * (c0 ? pp[e] : qq[e]);
        w0 = __int_as_float(__float_as_int(w0) & m0);
        S0 += w0;
        af0[e] = (short)__builtin_bit_cast(unsigned short, __float2bfloat16(w0));
        const bool c1 = pp[e] > T1;
        float w1 = (c1 ? A1 : B1) * (c1 ? pp[e] : qq[e]);
        w1 = __int_as_float(__float_as_int(w1) & m1);
        S1 += w1;
        af1[e] = (short)__builtin_bit_cast(unsigned short, __float2bfloat16(w1));
      }
      acc00 = __builtin_amdgcn_mfma_f32_16x16x32_bf16(af0, hv0, acc00, 0, 0, 0);
      acc01 = __builtin_amdgcn_mfma_f32_16x16x32_bf16(af0, hv1, acc01, 0, 0, 0);
      acc10 = __builtin_amdgcn_mfma_f32_16x16x32_bf16(af1, hv0, acc10, 0, 0, 0);
      acc11 = __builtin_amdgcn_mfma_f32_16x16x32_bf16(af1, hv1, acc11, 0, 0, 0);
    }
  }

  // denominator over this wave's j-quarter (sum the 4 k-groups)
  S0 += __shfl_xor(S0, 16); S0 += __shfl_xor(S0, 32);
  S1 += __shfl_xor(S1, 16); S1 += __shfl_xor(S1, 32);

#pragma unroll
  for (int r = 0; r < 4; ++r) {
    const int rl = lg * 4 + r;   // C row = (lane>>4)*4 + reg
    part[w][rl][lm] = acc00[r];
    part[w][rl][16 + lm] = acc01[r];
    part[w][16 + rl][lm] = acc10[r];
    part[w][16 + rl][16 + lm] = acc11[r];
  }
  if (lg == 0) { sp[w][0][lm] = S0; sp[w][1][lm] = S1; }
  __syncthreads();

  const int tid = threadIdx.x;
#pragma unroll
  for (int t = 0; t < 4; ++t) {
    const int idx = t * 256 + tid;
    const int row = idx >> 5, d = idx & 31;
    const float v = part[0][row][d] + part[1][row][d] +
                    part[2][row][d] + part[3][row][d];
    const float s = sp[0][row >> 4][row & 15] + sp[1][row >> 4][row & 15] +
                    sp[2][row >> 4][row & 15] + sp[3][row >> 4][row & 15];
    const float o = v / s;
    const int n = it * 32 + row;
    out[((size_t)b * NN + n) * 128 + head * 32 + d] =
        o > 0.f ? o : (__expf(o) - 1.f);
  }
}

extern "C" void kernel_launch(void* const* d_in, const int* in_sizes, int n_in,
                              void* d_out, int out_size, void* d_ws, size_t ws_size,
                              hipStream_t stream) {
  const float* x = (const float*)d_in[0];
  const int* adj = (const int*)d_in[1];
  const float* W = (const float*)d_in[2];
  const float* a = (const float*)d_in[3];
  float* out = (float*)d_out;
  float* ws = (float*)d_ws;

  float* e_src = ws + OFF_ES;
  float* e_dst = ws + OFF_ED;
  float* Pv = ws + OFF_P;
  float* Qv = ws + OFF_Q;
  float* Mv = ws + OFF_M;
  u16* hT = (u16*)(ws + OFF_HT);
  u32* bits = (u32*)(ws + OFF_BITS);

  k_pack<<<(BB * NN) / 4, 256, 0, stream>>>(adj, bits);
  k_proj<<<(BB * NN) / 16, 256, 0, stream>>>(x, W, a, hT, e_src, e_dst);
  k_prep<<<BB * NH * 8, 64, 0, stream>>>(e_dst, Pv, Qv, Mv);
  k_attn<<<BB * NH * 64, 256, 0, stream>>>(hT, e_src, Pv, Qv, Mv, bits, out);
}